// Round 5
// baseline (10.641 us; speedup 1.0000x reference)
//
#include <hip/hip_runtime.h>

// RelationNetwork collapsed algebraically (pair sum is linear):
//   X_A[b,d] = sum_i (N-1-i)*obj[b,i,d]
//   X_B[b,d] = sum_i  i     *obj[b,i,d]
//   s[b,e]   = P*bg[e] + sum_d Wg[e,d]*X_A[b,d] + Wg[e,64+d]*X_B[b,d]
//   out[b,f] = bf[f] + sum_e Wf[f,e]*s[b,e]
//
// Single dispatch, 65 blocks: 64 workers + 1 combiner. All cross-block
// traffic (packed float2 partials + flags) via agent-scope atomics (per-XCD
// L2 non-coherence; plain loads failed post-timing in R2). Combiner
// prefetches Wg (float2-packed A|B), Wf (transposed), bg, bf during the
// worker window; tail = flag hop -> 16 packed loads -> 2-read/iter GEMV.

#define NB 4
#define NN 1024
#define DD 64
#define NC 16
#define NCHUNK (NB * NC)    // 64 worker blocks
#define RPC (NN / NC)       // 64 rows per chunk
#define MAGIC 0x5A17C0DEu

__global__ __launch_bounds__(256) void rn_fused(const float* __restrict__ obj,
                                                const float* __restrict__ Wg,
                                                const float* __restrict__ bg,
                                                const float* __restrict__ Wf,
                                                const float* __restrict__ bf,
                                                float* __restrict__ out,
                                                float2* __restrict__ pAB,
                                                unsigned int* __restrict__ flags) {
    const int blk = blockIdx.x;
    const int t   = threadIdx.x;

    if (blk != 0) {
        // ================= worker: one 64-row chunk =================
        const int chunk = blk - 1;
        const int b  = chunk >> 4;
        const int c  = chunk & 15;
        const int dq = t & 15;     // float4 column
        const int r  = t >> 4;     // 0..15

        __shared__ float4 s4A[16][16];
        __shared__ float4 s4B[16][16];

        const float4* base4 = (const float4*)(obj + (size_t)b * NN * DD);
        float4 aA = {0.f, 0.f, 0.f, 0.f};
        float4 aB = {0.f, 0.f, 0.f, 0.f};
        #pragma unroll
        for (int p = 0; p < 4; ++p) {
            const int i = c * RPC + p * 16 + r;
            const float4 x = base4[i * 16 + dq];
            const float wA = (float)(NN - 1 - i);
            const float wB = (float)i;
            aA.x += wA * x.x; aA.y += wA * x.y; aA.z += wA * x.z; aA.w += wA * x.w;
            aB.x += wB * x.x; aB.y += wB * x.y; aB.z += wB * x.z; aB.w += wB * x.w;
        }
        s4A[r][dq] = aA;
        s4B[r][dq] = aB;
        __syncthreads();

        if (t < DD) {
            const int q = t >> 2, k = t & 3;
            float sa = 0.f, sb = 0.f;
            #pragma unroll
            for (int rr = 0; rr < 16; ++rr) {
                sa += ((const float*)&s4A[rr][q])[k];
                sb += ((const float*)&s4B[rr][q])[k];
            }
            union { float2 f2; unsigned long long u; } pk;
            pk.f2 = make_float2(sa, sb);
            __hip_atomic_store((unsigned long long*)&pAB[chunk * DD + t], pk.u,
                               __ATOMIC_RELAXED, __HIP_MEMORY_SCOPE_AGENT);
        }
        __syncthreads();   // partial stores sequenced before flag release

        if (t == 0)
            __hip_atomic_store(&flags[blk], MAGIC, __ATOMIC_RELEASE,
                               __HIP_MEMORY_SCOPE_AGENT);
        return;
    }

    // ================= combiner (block 0) =================
    __shared__ float2 sWgP[DD][DD + 1];   // [dd][e] = {WgA[e][dd], WgB[e][dd]}
    __shared__ float  sWfT[DD][DD + 1];   // [e][f]  = Wf[f][e]
    __shared__ float2 sXP[NB][DD];        // {XA, XB}
    __shared__ float  sS[NB][DD];

    const int x = t & 63;

    // ---- prefetch (overlaps worker execution; off the critical tail) ----
    const float rbg = bg[x];
    const float rbf = bf[x];

    const float4* wg4 = (const float4*)Wg;  // 64 rows x 32 float4
    #pragma unroll
    for (int k = 0; k < 8; ++k) {
        const int F = t + k * 256;          // 0..2047
        const float4 v = wg4[F];
        const int e = F >> 5, q = F & 31;   // q: float4 col within the 128-row
        if (q < 16) {                       // A-half: dd = q*4+j
            sWgP[q * 4 + 0][e].x = v.x;
            sWgP[q * 4 + 1][e].x = v.y;
            sWgP[q * 4 + 2][e].x = v.z;
            sWgP[q * 4 + 3][e].x = v.w;
        } else {                            // B-half: dd = (q-16)*4+j
            sWgP[(q - 16) * 4 + 0][e].y = v.x;
            sWgP[(q - 16) * 4 + 1][e].y = v.y;
            sWgP[(q - 16) * 4 + 2][e].y = v.z;
            sWgP[(q - 16) * 4 + 3][e].y = v.w;
        }
    }
    const float4* wf4 = (const float4*)Wf;  // 64 rows x 16 float4
    #pragma unroll
    for (int k = 0; k < 4; ++k) {
        const int F = t + k * 256;          // 0..1023
        const float4 v = wf4[F];
        const int f = F >> 4, eq = F & 15;
        sWfT[eq * 4 + 0][f] = v.x;
        sWfT[eq * 4 + 1][f] = v.y;
        sWfT[eq * 4 + 2][f] = v.z;
        sWfT[eq * 4 + 3][f] = v.w;
    }

    // ---- wait for the 64 workers ----
    if (t < NCHUNK) {
        while (__hip_atomic_load(&flags[t + 1], __ATOMIC_ACQUIRE,
                                 __HIP_MEMORY_SCOPE_AGENT) != MAGIC) {
            __builtin_amdgcn_s_sleep(2);
        }
    }
    __syncthreads();

    // ---- reduce partials -> packed {XA, XB} ----
    const int fb = t >> 6;  // batch 0..3 (wave-uniform)

    float a = 0.f, bb = 0.f;
    #pragma unroll
    for (int cc = 0; cc < NC; ++cc) {
        union { float2 f2; unsigned long long u; } pk;
        pk.u = __hip_atomic_load(
            (const unsigned long long*)&pAB[(fb * NC + cc) * DD + x],
            __ATOMIC_RELAXED, __HIP_MEMORY_SCOPE_AGENT);
        a  += pk.f2.x;
        bb += pk.f2.y;
    }
    sXP[fb][x] = make_float2(a, bb);
    __syncthreads();

    // ---- s[b,e] = P*bg[e] + sum_dd {WgA,WgB}[dd][e] . {XA,XB}[b][dd] ----
    const float PAIRS = 523776.f;  // 1024*1023/2
    float s = PAIRS * rbg;
    #pragma unroll
    for (int dd = 0; dd < 64; ++dd) {
        const float2 w  = sWgP[dd][x];      // ds_read_b64, 2-way alias (free)
        const float2 xp = sXP[fb][dd];      // wave-uniform broadcast
        s += w.x * xp.x + w.y * xp.y;
    }
    sS[fb][x] = s;
    __syncthreads();

    // ---- out[b,f] = bf[f] + Wf[f,:].s[b,:] ----
    float o = rbf;
    #pragma unroll
    for (int e = 0; e < 64; ++e) {
        o += sWfT[e][x] * sS[fb][e];
    }
    out[fb * 64 + x] = o;

    // reset flags for next replay — after the tail, fire-and-forget
    // (agent-scope atomic; flushed by kernel completion, stream-ordered)
    if (t < NCHUNK)
        __hip_atomic_store(&flags[t + 1], 0u, __ATOMIC_RELAXED,
                           __HIP_MEMORY_SCOPE_AGENT);
}

extern "C" void kernel_launch(void* const* d_in, const int* in_sizes, int n_in,
                              void* d_out, int out_size, void* d_ws, size_t ws_size,
                              hipStream_t stream) {
    const float* obj = (const float*)d_in[0];
    const float* Wg  = (const float*)d_in[1];
    const float* bg  = (const float*)d_in[2];
    const float* Wf  = (const float*)d_in[3];
    const float* bf  = (const float*)d_in[4];
    float* outp = (float*)d_out;

    float2* pAB = (float2*)d_ws;                               // [64][64] float2
    unsigned int* flags = (unsigned int*)(pAB + NCHUNK * DD);  // [65] u32

    rn_fused<<<NCHUNK + 1, 256, 0, stream>>>(obj, Wg, bg, Wf, bf, outp, pAB, flags);
}